// Round 4
// baseline (636.803 us; speedup 1.0000x reference)
//
#include <hip/hip_runtime.h>
#include <stdint.h>

// ---------- types ----------
typedef __bf16 bf16x8 __attribute__((ext_vector_type(8)));
typedef unsigned short u16x8 __attribute__((ext_vector_type(8)));
typedef float f32x4 __attribute__((ext_vector_type(4)));

#define SM_SCALE 4.419417382415922e-02f /* 1/22.627416997969522 */
#define DROP_SCALE (1.0f / 0.9f)

// ---------- helpers ----------
__device__ __forceinline__ unsigned short f2bf(float f) {
  uint32_t u = __float_as_uint(f);
  uint32_t r = (u + 0x7FFFu + ((u >> 16) & 1u)) >> 16;  // RNE
  return (unsigned short)r;
}

// JAX threefry2x32 with key (0,42). Core verified by hand against the
// Random123 KAT: key=(0,0), ctr=(0,0) -> (0x6B200159, 0x99BA4EFE). [r3]
__device__ __forceinline__ void threefry2x32(uint32_t x0, uint32_t x1,
                                             uint32_t& o0, uint32_t& o1) {
  const uint32_t K0 = 0u, K1 = 42u;
  const uint32_t K2 = K0 ^ K1 ^ 0x1BD11BDAu;
  x0 += K0; x1 += K1;
#define TF_R(rot) { x0 += x1; x1 = (x1 << rot) | (x1 >> (32 - rot)); x1 ^= x0; }
  TF_R(13) TF_R(15) TF_R(26) TF_R(6)  x0 += K1; x1 += K2 + 1u;
  TF_R(17) TF_R(29) TF_R(16) TF_R(24) x0 += K2; x1 += K0 + 2u;
  TF_R(13) TF_R(15) TF_R(26) TF_R(6)  x0 += K0; x1 += K1 + 3u;
  TF_R(17) TF_R(29) TF_R(16) TF_R(24) x0 += K1; x1 += K2 + 4u;
  TF_R(13) TF_R(15) TF_R(26) TF_R(6)  x0 += K2; x1 += K0 + 5u;
#undef TF_R
  o0 = x0; o1 = x1;
}

// keep-mask, JAX partitionable threefry (default in modern JAX):
// per-element counter mode, ctr = (hi32(idx)=0, lo32(idx)=idx).
// For bit_width < 64, random_bits returns the XOR-FOLD of the two output
// words: bits = bits1 ^ bits2 (the 64-bit block is only built for 64-bit).
__device__ __forceinline__ bool drop_keep(uint32_t idx) {
  uint32_t o0, o1;
  threefry2x32(0u, idx, o0, o1);
  uint32_t bits = o0 ^ o1;
  float u = __uint_as_float((bits >> 9) | 0x3f800000u) - 1.0f;  // [0,1)
  return u < 0.9f;
}

// ---------- kernel 1: value[512][4096] f32 -> valueT[4096][512] bf16 ----------
__global__ __launch_bounds__(256) void k_vt(const float* __restrict__ v,
                                            unsigned short* __restrict__ vt) {
  __shared__ float tile[32][33];
  const int nb = blockIdx.x;   // 0..127
  const int kb = blockIdx.y;   // 0..15
  const int tx = threadIdx.x & 31, ty = threadIdx.x >> 5;  // 32 x 8
#pragma unroll
  for (int yy = 0; yy < 4; ++yy) {
    int row = ty + yy * 8;
    tile[row][tx] = v[(size_t)(kb * 32 + row) * 4096 + nb * 32 + tx];
  }
  __syncthreads();
#pragma unroll
  for (int yy = 0; yy < 4; ++yy) {
    int row = ty + yy * 8;
    vt[(size_t)(nb * 32 + row) * 512 + kb * 32 + tx] = f2bf(tile[tx][row]);
  }
}

// ---------- kernel 2: QK^T (pure f32 VALU) + softmax + dropout -> P bf16 ----------
// Block: 512 thr = 8 waves. Wave tr owns rows brow+tr*8 .. +8 (all 512 cols).
// Lane tc owns cols {tc + 64*ci}. Softmax is a full-wave shfl reduce. No LDS.
__global__ __launch_bounds__(512) void k_qk(const float* __restrict__ in1,
                                            const float* __restrict__ in2,
                                            unsigned short* __restrict__ P) {
  const int tid = threadIdx.x;
  const int tc = tid & 63, tr = tid >> 6;
  const int brow = blockIdx.x * 64;

  float acc[8][8] = {};  // [ri][ci]

  for (int k = 0; k < 512; k += 4) {
    float4 a4[8], b4[8];
#pragma unroll
    for (int ri = 0; ri < 8; ++ri)
      a4[ri] = *reinterpret_cast<const float4*>(
          in1 + (size_t)(brow + tr * 8 + ri) * 512 + k);  // wave-broadcast
#pragma unroll
    for (int ci = 0; ci < 8; ++ci)
      b4[ci] = *reinterpret_cast<const float4*>(
          in2 + (size_t)(tc + ci * 64) * 512 + k);        // per-lane row
#pragma unroll
    for (int ri = 0; ri < 8; ++ri)
#pragma unroll
      for (int ci = 0; ci < 8; ++ci) {
        acc[ri][ci] += a4[ri].x * b4[ci].x;
        acc[ri][ci] += a4[ri].y * b4[ci].y;
        acc[ri][ci] += a4[ri].z * b4[ci].z;
        acc[ri][ci] += a4[ri].w * b4[ci].w;
      }
  }

#pragma unroll
  for (int ri = 0; ri < 8; ++ri) {
    float m = -1e30f;
#pragma unroll
    for (int ci = 0; ci < 8; ++ci) {
      acc[ri][ci] *= SM_SCALE;
      m = fmaxf(m, acc[ri][ci]);
    }
#pragma unroll
    for (int s = 1; s < 64; s <<= 1) m = fmaxf(m, __shfl_xor(m, s, 64));
    float sum = 0.f;
#pragma unroll
    for (int ci = 0; ci < 8; ++ci) {
      float e = expf(acc[ri][ci] - m);
      acc[ri][ci] = e;
      sum += e;
    }
#pragma unroll
    for (int s = 1; s < 64; s <<= 1) sum += __shfl_xor(sum, s, 64);
    const float scl = DROP_SCALE / sum;
    const uint32_t row = (uint32_t)(brow + tr * 8 + ri);
#pragma unroll
    for (int ci = 0; ci < 8; ++ci) {
      uint32_t idx = row * 512u + (uint32_t)(tc + ci * 64);
      float pv = drop_keep(idx) ? acc[ri][ci] * scl : 0.0f;
      P[idx] = f2bf(pv);
    }
  }
}

// ---------- kernel 3: out = P[16384][512] @ vT[4096][512]^T (bf16 MFMA) ----------
// 128x128 tile, BK=64, 4 waves (2x2, each 64x64). Reg-staged LDS, +8 pad, linear.
__global__ __launch_bounds__(256) void k_pv(const unsigned short* __restrict__ P,
                                            const unsigned short* __restrict__ VT,
                                            float* __restrict__ out) {
  __shared__ unsigned short lA[128][72];  // 72 = 64 + 8 pad (16B-aligned rows)
  __shared__ unsigned short lB[128][72];
  const int tid = threadIdx.x;
  const int l = tid & 63, w = tid >> 6;
  const int wr = w >> 1, wc = w & 1;
  const int g = l >> 4, c16 = l & 15;

  // XCD-aware bijective swizzle (4096 % 8 == 0)
  const int bid = blockIdx.x;
  const int x = (bid & 7) * 512 + (bid >> 3);
  const int brow = (x >> 5) * 128;   // 128 row-tiles
  const int bcol = (x & 31) * 128;   // 32 col-tiles

  f32x4 acc[4][4] = {};

  for (int kt = 0; kt < 8; ++kt) {
    const int k0 = kt * 64;
#pragma unroll
    for (int i = 0; i < 4; ++i) {
      int c = i * 256 + tid;          // 0..1023 chunks of 8 shorts
      int row = c >> 3, sub = c & 7;
      u16x8 va = *reinterpret_cast<const u16x8*>(
          P + (size_t)(brow + row) * 512 + k0 + sub * 8);
      u16x8 vb = *reinterpret_cast<const u16x8*>(
          VT + (size_t)(bcol + row) * 512 + k0 + sub * 8);
      *reinterpret_cast<u16x8*>(&lA[row][sub * 8]) = va;
      *reinterpret_cast<u16x8*>(&lB[row][sub * 8]) = vb;
    }
    __syncthreads();

#pragma unroll
    for (int kk = 0; kk < 64; kk += 32) {
      bf16x8 a[4], b[4];
#pragma unroll
      for (int i = 0; i < 4; ++i)
        a[i] = *reinterpret_cast<const bf16x8*>(&lA[wr * 64 + i * 16 + c16][kk + g * 8]);
#pragma unroll
      for (int j = 0; j < 4; ++j)
        b[j] = *reinterpret_cast<const bf16x8*>(&lB[wc * 64 + j * 16 + c16][kk + g * 8]);
#pragma unroll
      for (int i = 0; i < 4; ++i)
#pragma unroll
        for (int j = 0; j < 4; ++j)
          acc[i][j] = __builtin_amdgcn_mfma_f32_16x16x32_bf16(a[i], b[j], acc[i][j], 0, 0, 0);
    }
    __syncthreads();
  }

  // C/D layout (verified m89/m91): col = lane&15, row = (lane>>4)*4 + reg
#pragma unroll
  for (int i = 0; i < 4; ++i)
#pragma unroll
    for (int r = 0; r < 4; ++r) {
      const size_t row = (size_t)(brow + wr * 64 + i * 16 + g * 4 + r);
      float* o = out + row * 4096 + bcol + wc * 64 + c16;
#pragma unroll
      for (int j = 0; j < 4; ++j) o[j * 16] = acc[i][j][r];
    }
}

// ---------- launch ----------
extern "C" void kernel_launch(void* const* d_in, const int* in_sizes, int n_in,
                              void* d_out, int out_size, void* d_ws, size_t ws_size,
                              hipStream_t stream) {
  (void)in_sizes; (void)n_in; (void)out_size; (void)ws_size;
  const float* in1   = (const float*)d_in[0];   // [16384][512]
  const float* in2   = (const float*)d_in[1];   // [512][512]
  const float* value = (const float*)d_in[2];   // [512][4096]
  float* out = (float*)d_out;                   // [16384][4096]

  unsigned short* vT = (unsigned short*)d_ws;   // 4 MB  [4096][512] bf16
  unsigned short* Pb = vT + 2097152;            // 16 MB [16384][512] bf16

  k_vt<<<dim3(128, 16), dim3(256), 0, stream>>>(value, vT);
  k_qk<<<dim3(256), dim3(512), 0, stream>>>(in1, in2, Pb);
  k_pv<<<dim3(4096), dim3(256), 0, stream>>>(Pb, vT, out);
}

// Round 5
// 202.753 us; speedup vs baseline: 3.1408x; 3.1408x over previous
//
#include <hip/hip_runtime.h>
#include <stdint.h>

// ---------- types ----------
typedef __bf16 bf16x8 __attribute__((ext_vector_type(8)));
typedef unsigned short u16x8 __attribute__((ext_vector_type(8)));
typedef float f32x4 __attribute__((ext_vector_type(4)));

#define SM_SCALE 4.419417382415922e-02f /* 1/22.627416997969522 */
#define DROP_SCALE (1.0f / 0.9f)

// ---------- helpers ----------
__device__ __forceinline__ unsigned short f2bf(float f) {
  uint32_t u = __float_as_uint(f);
  uint32_t r = (u + 0x7FFFu + ((u >> 16) & 1u)) >> 16;  // RNE
  return (unsigned short)r;
}
__device__ __forceinline__ float bf2f(unsigned short h) {
  return __uint_as_float(((uint32_t)h) << 16);
}

// JAX threefry2x32 with key (0,42). [validated r4]
__device__ __forceinline__ void threefry2x32(uint32_t x0, uint32_t x1,
                                             uint32_t& o0, uint32_t& o1) {
  const uint32_t K0 = 0u, K1 = 42u;
  const uint32_t K2 = K0 ^ K1 ^ 0x1BD11BDAu;
  x0 += K0; x1 += K1;
#define TF_R(rot) { x0 += x1; x1 = (x1 << rot) | (x1 >> (32 - rot)); x1 ^= x0; }
  TF_R(13) TF_R(15) TF_R(26) TF_R(6)  x0 += K1; x1 += K2 + 1u;
  TF_R(17) TF_R(29) TF_R(16) TF_R(24) x0 += K2; x1 += K0 + 2u;
  TF_R(13) TF_R(15) TF_R(26) TF_R(6)  x0 += K0; x1 += K1 + 3u;
  TF_R(17) TF_R(29) TF_R(16) TF_R(24) x0 += K1; x1 += K2 + 4u;
  TF_R(13) TF_R(15) TF_R(26) TF_R(6)  x0 += K2; x1 += K0 + 5u;
#undef TF_R
  o0 = x0; o1 = x1;
}

// keep-mask, JAX partitionable threefry, ctr=(0,idx), XOR-fold. [validated r4]
__device__ __forceinline__ bool drop_keep(uint32_t idx) {
  uint32_t o0, o1;
  threefry2x32(0u, idx, o0, o1);
  uint32_t bits = o0 ^ o1;
  float u = __uint_as_float((bits >> 9) | 0x3f800000u) - 1.0f;  // [0,1)
  return u < 0.9f;
}

// ---------- kernel 1: value[512][4096] f32 -> valueT[4096][512] bf16 [validated r4] ----
__global__ __launch_bounds__(256) void k_vt(const float* __restrict__ v,
                                            unsigned short* __restrict__ vt) {
  __shared__ float tile[32][33];
  const int nb = blockIdx.x;   // 0..127
  const int kb = blockIdx.y;   // 0..15
  const int tx = threadIdx.x & 31, ty = threadIdx.x >> 5;  // 32 x 8
#pragma unroll
  for (int yy = 0; yy < 4; ++yy) {
    int row = ty + yy * 8;
    tile[row][tx] = v[(size_t)(kb * 32 + row) * 4096 + nb * 32 + tx];
  }
  __syncthreads();
#pragma unroll
  for (int yy = 0; yy < 4; ++yy) {
    int row = ty + yy * 8;
    vt[(size_t)(nb * 32 + row) * 512 + kb * 32 + tx] = f2bf(tile[tx][row]);
  }
}

// ---------- kernel 1b: in2 f32 -> bf16 hi/lo split ----------
__global__ __launch_bounds__(256) void k_split(const float* __restrict__ src,
                                               unsigned short* __restrict__ hi,
                                               unsigned short* __restrict__ lo,
                                               int n4) {
  int i = blockIdx.x * 256 + threadIdx.x;
  if (i >= n4) return;
  float4 v = reinterpret_cast<const float4*>(src)[i];
  ushort4 h, l;
  h.x = f2bf(v.x); l.x = f2bf(v.x - bf2f(h.x));
  h.y = f2bf(v.y); l.y = f2bf(v.y - bf2f(h.y));
  h.z = f2bf(v.z); l.z = f2bf(v.z - bf2f(h.z));
  h.w = f2bf(v.w); l.w = f2bf(v.w - bf2f(h.w));
  reinterpret_cast<ushort4*>(hi)[i] = h;
  reinterpret_cast<ushort4*>(lo)[i] = l;
}

// ---------- kernel 2: QK^T (split-bf16 MFMA, f32-accurate logits) + softmax
//                      + dropout -> P bf16 ----------
// 512 thr = 8 waves (4 row-groups x 2 col-halves). 64 rows x 512 cols / block.
// K-tile 32; per tile: stage Bhi (+A hi/lo), 2 MFMA/j; stage Blo, 1 MFMA/j.
__global__ __launch_bounds__(512) void k_qk(const float* __restrict__ in1,
                                            const unsigned short* __restrict__ B2hi,
                                            const unsigned short* __restrict__ B2lo,
                                            unsigned short* __restrict__ P) {
  __shared__ unsigned short lB[512][40];    // 40 KB   [col][k], pad->80B rows
  __shared__ unsigned short lAhi[64][40];   // 5 KB
  __shared__ unsigned short lAlo[64][40];   // 5 KB
  __shared__ float redm[2][64], reds[2][64];

  const int tid = threadIdx.x;
  const int l = tid & 63, w = tid >> 6;
  const int wr = w >> 1, wc = w & 1;        // 4 x 2 wave grid
  const int g = l >> 4, c16 = l & 15;
  const int brow = blockIdx.x * 64;

  f32x4 acc[16] = {};

  for (int kt = 0; kt < 16; ++kt) {
    const int k0 = kt * 32;
    // ---- phase 1: stage Bhi tile [512][32] + A hi/lo [64][32] ----
#pragma unroll
    for (int i = 0; i < 4; ++i) {
      int c = i * 512 + tid;                 // 2048 chunks of 8 shorts
      int col = c >> 2, sub = c & 3;
      u16x8 vb = *reinterpret_cast<const u16x8*>(B2hi + (size_t)col * 512 + k0 + sub * 8);
      *reinterpret_cast<u16x8*>(&lB[col][sub * 8]) = vb;
    }
    {
      int row = tid >> 3, sub = tid & 7;    // 512 chunks of float4
      float4 v = *reinterpret_cast<const float4*>(in1 + (size_t)(brow + row) * 512 + k0 + sub * 4);
      ushort4 h, lo4;
      h.x = f2bf(v.x); lo4.x = f2bf(v.x - bf2f(h.x));
      h.y = f2bf(v.y); lo4.y = f2bf(v.y - bf2f(h.y));
      h.z = f2bf(v.z); lo4.z = f2bf(v.z - bf2f(h.z));
      h.w = f2bf(v.w); lo4.w = f2bf(v.w - bf2f(h.w));
      *reinterpret_cast<ushort4*>(&lAhi[row][sub * 4]) = h;
      *reinterpret_cast<ushort4*>(&lAlo[row][sub * 4]) = lo4;
    }
    __syncthreads();

    const int arow = wr * 16 + c16;
    bf16x8 ahi = *reinterpret_cast<const bf16x8*>(&lAhi[arow][g * 8]);
    bf16x8 alo = *reinterpret_cast<const bf16x8*>(&lAlo[arow][g * 8]);
#pragma unroll
    for (int j = 0; j < 16; ++j) {
      const int col = wc * 256 + j * 16 + c16;
      bf16x8 bh = *reinterpret_cast<const bf16x8*>(&lB[col][g * 8]);
      acc[j] = __builtin_amdgcn_mfma_f32_16x16x32_bf16(ahi, bh, acc[j], 0, 0, 0);
      acc[j] = __builtin_amdgcn_mfma_f32_16x16x32_bf16(alo, bh, acc[j], 0, 0, 0);
    }
    __syncthreads();

    // ---- phase 2: stage Blo tile over lB ----
#pragma unroll
    for (int i = 0; i < 4; ++i) {
      int c = i * 512 + tid;
      int col = c >> 2, sub = c & 3;
      u16x8 vb = *reinterpret_cast<const u16x8*>(B2lo + (size_t)col * 512 + k0 + sub * 8);
      *reinterpret_cast<u16x8*>(&lB[col][sub * 8]) = vb;
    }
    __syncthreads();
#pragma unroll
    for (int j = 0; j < 16; ++j) {
      const int col = wc * 256 + j * 16 + c16;
      bf16x8 bl = *reinterpret_cast<const bf16x8*>(&lB[col][g * 8]);
      acc[j] = __builtin_amdgcn_mfma_f32_16x16x32_bf16(ahi, bl, acc[j], 0, 0, 0);
    }
    __syncthreads();
  }

  // ---- epilogue: scale, softmax over 512 cols, dropout, write P bf16 ----
  // C/D layout [validated r4 in k_pv]: col = c16 (+j*16+wc*256), row = g*4 + r (+wr*16)
  const int rowbase = wr * 16 + g * 4;
  float mx[4] = {-3.4e38f, -3.4e38f, -3.4e38f, -3.4e38f};
#pragma unroll
  for (int j = 0; j < 16; ++j)
#pragma unroll
    for (int r = 0; r < 4; ++r) {
      acc[j][r] *= SM_SCALE;
      mx[r] = fmaxf(mx[r], acc[j][r]);
    }
#pragma unroll
  for (int s = 1; s < 16; s <<= 1)
#pragma unroll
    for (int r = 0; r < 4; ++r) mx[r] = fmaxf(mx[r], __shfl_xor(mx[r], s, 64));
  if (c16 == 0) {
#pragma unroll
    for (int r = 0; r < 4; ++r) redm[wc][rowbase + r] = mx[r];
  }
  __syncthreads();
  float rmax[4], sum[4] = {0.f, 0.f, 0.f, 0.f};
#pragma unroll
  for (int r = 0; r < 4; ++r)
    rmax[r] = fmaxf(redm[0][rowbase + r], redm[1][rowbase + r]);
#pragma unroll
  for (int j = 0; j < 16; ++j)
#pragma unroll
    for (int r = 0; r < 4; ++r) {
      float e = expf(acc[j][r] - rmax[r]);
      acc[j][r] = e;
      sum[r] += e;
    }
#pragma unroll
  for (int s = 1; s < 16; s <<= 1)
#pragma unroll
    for (int r = 0; r < 4; ++r) sum[r] += __shfl_xor(sum[r], s, 64);
  if (c16 == 0) {
#pragma unroll
    for (int r = 0; r < 4; ++r) reds[wc][rowbase + r] = sum[r];
  }
  __syncthreads();
  float scl[4];
#pragma unroll
  for (int r = 0; r < 4; ++r)
    scl[r] = DROP_SCALE / (reds[0][rowbase + r] + reds[1][rowbase + r]);

#pragma unroll
  for (int j = 0; j < 16; ++j) {
    const int col = wc * 256 + j * 16 + c16;
#pragma unroll
    for (int r = 0; r < 4; ++r) {
      uint32_t idx = (uint32_t)(brow + rowbase + r) * 512u + (uint32_t)col;
      float pv = drop_keep(idx) ? acc[j][r] * scl[r] : 0.0f;
      P[idx] = f2bf(pv);
    }
  }
}

// ---------- kernel 3: out = P[16384][512] @ vT[4096][512]^T (bf16 MFMA) [validated r4] --
__global__ __launch_bounds__(256) void k_pv(const unsigned short* __restrict__ P,
                                            const unsigned short* __restrict__ VT,
                                            float* __restrict__ out) {
  __shared__ unsigned short lA[128][72];
  __shared__ unsigned short lB[128][72];
  const int tid = threadIdx.x;
  const int l = tid & 63, w = tid >> 6;
  const int wr = w >> 1, wc = w & 1;
  const int g = l >> 4, c16 = l & 15;

  const int bid = blockIdx.x;
  const int x = (bid & 7) * 512 + (bid >> 3);
  const int brow = (x >> 5) * 128;
  const int bcol = (x & 31) * 128;

  f32x4 acc[4][4] = {};

  for (int kt = 0; kt < 8; ++kt) {
    const int k0 = kt * 64;
#pragma unroll
    for (int i = 0; i < 4; ++i) {
      int c = i * 256 + tid;
      int row = c >> 3, sub = c & 7;
      u16x8 va = *reinterpret_cast<const u16x8*>(P + (size_t)(brow + row) * 512 + k0 + sub * 8);
      u16x8 vb = *reinterpret_cast<const u16x8*>(VT + (size_t)(bcol + row) * 512 + k0 + sub * 8);
      *reinterpret_cast<u16x8*>(&lA[row][sub * 8]) = va;
      *reinterpret_cast<u16x8*>(&lB[row][sub * 8]) = vb;
    }
    __syncthreads();

#pragma unroll
    for (int kk = 0; kk < 64; kk += 32) {
      bf16x8 a[4], b[4];
#pragma unroll
      for (int i = 0; i < 4; ++i)
        a[i] = *reinterpret_cast<const bf16x8*>(&lA[wr * 64 + i * 16 + c16][kk + g * 8]);
#pragma unroll
      for (int j = 0; j < 4; ++j)
        b[j] = *reinterpret_cast<const bf16x8*>(&lB[wc * 64 + j * 16 + c16][kk + g * 8]);
#pragma unroll
      for (int i = 0; i < 4; ++i)
#pragma unroll
        for (int j = 0; j < 4; ++j)
          acc[i][j] = __builtin_amdgcn_mfma_f32_16x16x32_bf16(a[i], b[j], acc[i][j], 0, 0, 0);
    }
    __syncthreads();
  }

#pragma unroll
  for (int i = 0; i < 4; ++i)
#pragma unroll
    for (int r = 0; r < 4; ++r) {
      const size_t row = (size_t)(brow + wr * 64 + i * 16 + g * 4 + r);
      float* o = out + row * 4096 + bcol + wc * 64 + c16;
#pragma unroll
      for (int j = 0; j < 4; ++j) o[j * 16] = acc[i][j][r];
    }
}

// ---------- launch ----------
extern "C" void kernel_launch(void* const* d_in, const int* in_sizes, int n_in,
                              void* d_out, int out_size, void* d_ws, size_t ws_size,
                              hipStream_t stream) {
  (void)in_sizes; (void)n_in; (void)out_size; (void)ws_size;
  const float* in1   = (const float*)d_in[0];   // [16384][512]
  const float* in2   = (const float*)d_in[1];   // [512][512]
  const float* value = (const float*)d_in[2];   // [512][4096]
  float* out = (float*)d_out;                   // [16384][4096]

  unsigned short* vT    = (unsigned short*)d_ws;  // 4 MB   [4096][512] bf16
  unsigned short* Pb    = vT + 2097152;           // 16 MB  [16384][512] bf16
  unsigned short* in2hi = Pb + 8388608;           // 0.5 MB [512][512] bf16
  unsigned short* in2lo = in2hi + 262144;         // 0.5 MB

  k_vt<<<dim3(128, 16), dim3(256), 0, stream>>>(value, vT);
  k_split<<<dim3(256), dim3(256), 0, stream>>>(in2, in2hi, in2lo, 65536);
  k_qk<<<dim3(256), dim3(512), 0, stream>>>(in1, in2hi, in2lo, Pb);
  k_pv<<<dim3(4096), dim3(256), 0, stream>>>(Pb, vT, out);
}

// Round 6
// 201.669 us; speedup vs baseline: 3.1577x; 1.0054x over previous
//
#include <hip/hip_runtime.h>
#include <stdint.h>

// ---------- types ----------
typedef __bf16 bf16x8 __attribute__((ext_vector_type(8)));
typedef unsigned short u16x8 __attribute__((ext_vector_type(8)));
typedef float f32x4 __attribute__((ext_vector_type(4)));

#define SM_SCALE 4.419417382415922e-02f /* 1/22.627416997969522 */
#define DROP_SCALE (1.0f / 0.9f)

// ---------- helpers ----------
__device__ __forceinline__ unsigned short f2bf(float f) {
  uint32_t u = __float_as_uint(f);
  uint32_t r = (u + 0x7FFFu + ((u >> 16) & 1u)) >> 16;  // RNE
  return (unsigned short)r;
}
__device__ __forceinline__ float bf2f(unsigned short h) {
  return __uint_as_float(((uint32_t)h) << 16);
}

// async global->LDS, 16B/lane. LDS dest = wave-uniform base + lane*16.
__device__ __forceinline__ void async16(const void* g, void* l) {
  __builtin_amdgcn_global_load_lds(
      (__attribute__((address_space(1))) uint32_t*)g,
      (__attribute__((address_space(3))) uint32_t*)l, 16, 0, 0);
}

// JAX threefry2x32 with key (0,42). [validated r4]
__device__ __forceinline__ void threefry2x32(uint32_t x0, uint32_t x1,
                                             uint32_t& o0, uint32_t& o1) {
  const uint32_t K0 = 0u, K1 = 42u;
  const uint32_t K2 = K0 ^ K1 ^ 0x1BD11BDAu;
  x0 += K0; x1 += K1;
#define TF_R(rot) { x0 += x1; x1 = (x1 << rot) | (x1 >> (32 - rot)); x1 ^= x0; }
  TF_R(13) TF_R(15) TF_R(26) TF_R(6)  x0 += K1; x1 += K2 + 1u;
  TF_R(17) TF_R(29) TF_R(16) TF_R(24) x0 += K2; x1 += K0 + 2u;
  TF_R(13) TF_R(15) TF_R(26) TF_R(6)  x0 += K0; x1 += K1 + 3u;
  TF_R(17) TF_R(29) TF_R(16) TF_R(24) x0 += K1; x1 += K2 + 4u;
  TF_R(13) TF_R(15) TF_R(26) TF_R(6)  x0 += K2; x1 += K0 + 5u;
#undef TF_R
  o0 = x0; o1 = x1;
}

// keep-mask, JAX partitionable threefry, ctr=(0,idx), XOR-fold. [validated r4]
__device__ __forceinline__ bool drop_keep(uint32_t idx) {
  uint32_t o0, o1;
  threefry2x32(0u, idx, o0, o1);
  uint32_t bits = o0 ^ o1;
  float u = __uint_as_float((bits >> 9) | 0x3f800000u) - 1.0f;  // [0,1)
  return u < 0.9f;
}

// ---------- kernel 1: value[512][4096] f32 -> valueT[4096][512] bf16 [validated r4] ----
__global__ __launch_bounds__(256) void k_vt(const float* __restrict__ v,
                                            unsigned short* __restrict__ vt) {
  __shared__ float tile[32][33];
  const int nb = blockIdx.x;   // 0..127
  const int kb = blockIdx.y;   // 0..15
  const int tx = threadIdx.x & 31, ty = threadIdx.x >> 5;  // 32 x 8
#pragma unroll
  for (int yy = 0; yy < 4; ++yy) {
    int row = ty + yy * 8;
    tile[row][tx] = v[(size_t)(kb * 32 + row) * 4096 + nb * 32 + tx];
  }
  __syncthreads();
#pragma unroll
  for (int yy = 0; yy < 4; ++yy) {
    int row = ty + yy * 8;
    vt[(size_t)(nb * 32 + row) * 512 + kb * 32 + tx] = f2bf(tile[tx][row]);
  }
}

// ---------- kernel 1b: in2 f32 -> bf16 hi/lo split [validated r5] ----------
__global__ __launch_bounds__(256) void k_split(const float* __restrict__ src,
                                               unsigned short* __restrict__ hi,
                                               unsigned short* __restrict__ lo,
                                               int n4) {
  int i = blockIdx.x * 256 + threadIdx.x;
  if (i >= n4) return;
  float4 v = reinterpret_cast<const float4*>(src)[i];
  ushort4 h, l;
  h.x = f2bf(v.x); l.x = f2bf(v.x - bf2f(h.x));
  h.y = f2bf(v.y); l.y = f2bf(v.y - bf2f(h.y));
  h.z = f2bf(v.z); l.z = f2bf(v.z - bf2f(h.z));
  h.w = f2bf(v.w); l.w = f2bf(v.w - bf2f(h.w));
  reinterpret_cast<ushort4*>(hi)[i] = h;
  reinterpret_cast<ushort4*>(lo)[i] = l;
}

// ---------- kernel 2: QK^T (split-bf16 MFMA) + softmax + dropout -> P bf16 ----------
// v2: 512 blocks x 512 thr (8 waves, 2x4), 32 rows x 512 cols per block.
// A-fragments direct from global (in-register hi/lo split, no LDS, no barrier).
// B hi+lo staged together per K-tile -> 2 barriers/tile. 2 blocks/CU.
__global__ __launch_bounds__(512) void k_qk(const float* __restrict__ in1,
                                            const unsigned short* __restrict__ B2hi,
                                            const unsigned short* __restrict__ B2lo,
                                            unsigned short* __restrict__ P) {
  __shared__ unsigned short lB[512][72];  // [col][hi 0..31 | lo 32..63 | pad] 73.7KB
  __shared__ float redm[4][32], reds[4][32];

  const int tid = threadIdx.x;
  const int l = tid & 63, w = tid >> 6;
  const int wr = w >> 2, wc = w & 3;      // wave grid 2 x 4
  const int g = l >> 4, c16 = l & 15;
  const int brow = blockIdx.x * 32;

  f32x4 acc[8] = {};

  for (int kt = 0; kt < 16; ++kt) {
    const int k0 = kt * 32;
    // ---- stage B hi+lo tile [512 cols][32 k] each ----
#pragma unroll
    for (int i = 0; i < 8; ++i) {
      int c = i * 512 + tid;                // 4096 chunks of 8 shorts
      int col = c >> 3, half = (c >> 2) & 1, sub = c & 3;
      const unsigned short* src = (half ? B2lo : B2hi) + (size_t)col * 512 + k0 + sub * 8;
      *reinterpret_cast<u16x8*>(&lB[col][half * 32 + sub * 8]) =
          *reinterpret_cast<const u16x8*>(src);
    }
    // ---- A fragment direct from global, split in-register ----
    const int arow = brow + wr * 16 + c16;
    float4 v0 = *reinterpret_cast<const float4*>(in1 + (size_t)arow * 512 + k0 + g * 8);
    float4 v1 = *reinterpret_cast<const float4*>(in1 + (size_t)arow * 512 + k0 + g * 8 + 4);
    bf16x8 ahi, alo;
    {
      float vv[8] = {v0.x, v0.y, v0.z, v0.w, v1.x, v1.y, v1.z, v1.w};
      unsigned short h[8], lo8[8];
#pragma unroll
      for (int e = 0; e < 8; ++e) {
        h[e] = f2bf(vv[e]);
        lo8[e] = f2bf(vv[e] - bf2f(h[e]));
      }
      ahi = *reinterpret_cast<const bf16x8*>(h);
      alo = *reinterpret_cast<const bf16x8*>(lo8);
    }
    __syncthreads();
#pragma unroll
    for (int j = 0; j < 8; ++j) {
      const int col = wc * 128 + j * 16 + c16;
      bf16x8 bh = *reinterpret_cast<const bf16x8*>(&lB[col][g * 8]);
      bf16x8 bl = *reinterpret_cast<const bf16x8*>(&lB[col][32 + g * 8]);
      acc[j] = __builtin_amdgcn_mfma_f32_16x16x32_bf16(ahi, bh, acc[j], 0, 0, 0);
      acc[j] = __builtin_amdgcn_mfma_f32_16x16x32_bf16(alo, bh, acc[j], 0, 0, 0);
      acc[j] = __builtin_amdgcn_mfma_f32_16x16x32_bf16(ahi, bl, acc[j], 0, 0, 0);
    }
    __syncthreads();
  }

  // ---- epilogue: scale, softmax over 512 cols, dropout, write P bf16 ----
  // C/D layout: col = c16 (+j*16+wc*128), row = g*4 + r (+wr*16)
  const int rowbase = wr * 16 + g * 4;
  float mx[4] = {-3.4e38f, -3.4e38f, -3.4e38f, -3.4e38f};
#pragma unroll
  for (int j = 0; j < 8; ++j)
#pragma unroll
    for (int r = 0; r < 4; ++r) {
      acc[j][r] *= SM_SCALE;
      mx[r] = fmaxf(mx[r], acc[j][r]);
    }
#pragma unroll
  for (int s = 1; s < 16; s <<= 1)
#pragma unroll
    for (int r = 0; r < 4; ++r) mx[r] = fmaxf(mx[r], __shfl_xor(mx[r], s, 64));
  if (c16 == 0) {
#pragma unroll
    for (int r = 0; r < 4; ++r) redm[wc][rowbase + r] = mx[r];
  }
  __syncthreads();
  float rmax[4], sum[4] = {0.f, 0.f, 0.f, 0.f};
#pragma unroll
  for (int r = 0; r < 4; ++r)
    rmax[r] = fmaxf(fmaxf(redm[0][rowbase + r], redm[1][rowbase + r]),
                    fmaxf(redm[2][rowbase + r], redm[3][rowbase + r]));
#pragma unroll
  for (int j = 0; j < 8; ++j)
#pragma unroll
    for (int r = 0; r < 4; ++r) {
      float e = expf(acc[j][r] - rmax[r]);
      acc[j][r] = e;
      sum[r] += e;
    }
#pragma unroll
  for (int s = 1; s < 16; s <<= 1)
#pragma unroll
    for (int r = 0; r < 4; ++r) sum[r] += __shfl_xor(sum[r], s, 64);
  if (c16 == 0) {
#pragma unroll
    for (int r = 0; r < 4; ++r) reds[wc][rowbase + r] = sum[r];
  }
  __syncthreads();
  float scl[4];
#pragma unroll
  for (int r = 0; r < 4; ++r)
    scl[r] = DROP_SCALE / (reds[0][rowbase + r] + reds[1][rowbase + r] +
                           reds[2][rowbase + r] + reds[3][rowbase + r]);

#pragma unroll
  for (int j = 0; j < 8; ++j) {
    const int col = wc * 128 + j * 16 + c16;
#pragma unroll
    for (int r = 0; r < 4; ++r) {
      uint32_t idx = (uint32_t)(brow + rowbase + r) * 512u + (uint32_t)col;
      float pv = drop_keep(idx) ? acc[j][r] * scl[r] : 0.0f;
      P[idx] = f2bf(pv);
    }
  }
}

// ---------- kernel 3: out = P[16384][512] @ vT[4096][512]^T (bf16 MFMA) ----------
// v2: global_load_lds staging, linear LDS dest + inverse-swizzled global source
// (slot^(row&7)) + same XOR on ds_read (rule #21). 128x128 tile, BK=64, 4 waves.
__global__ __launch_bounds__(256) void k_pv(const unsigned short* __restrict__ P,
                                            const unsigned short* __restrict__ VT,
                                            float* __restrict__ out) {
  __shared__ unsigned short lA[128][64];  // linear, no pad (gload_lds dest)
  __shared__ unsigned short lB[128][64];
  const int tid = threadIdx.x;
  const int l = tid & 63, w = tid >> 6;
  const int wr = w >> 1, wc = w & 1;
  const int g = l >> 4, c16 = l & 15;

  const int bid = blockIdx.x;
  const int x = (bid & 7) * 512 + (bid >> 3);  // XCD-aware, bijective (4096%8==0)
  const int brow = (x >> 5) * 128;
  const int bcol = (x & 31) * 128;

  f32x4 acc[4][4] = {};

  for (int kt = 0; kt < 8; ++kt) {
    const int k0 = kt * 64;
#pragma unroll
    for (int i = 0; i < 4; ++i) {
      int c = i * 256 + tid;                 // 1024 chunks of 16B per matrix
      int row = c >> 3, slot = c & 7;
      int gsub = slot ^ (row & 7);           // inverse-swizzled source
      async16(P + (size_t)(brow + row) * 512 + k0 + gsub * 8,
              lA[0] + (size_t)(i * 256 + w * 64) * 8);
      async16(VT + (size_t)(bcol + row) * 512 + k0 + gsub * 8,
              lB[0] + (size_t)(i * 256 + w * 64) * 8);
    }
    asm volatile("s_waitcnt vmcnt(0)" ::: "memory");
    __syncthreads();

#pragma unroll
    for (int kk = 0; kk < 64; kk += 32) {
      bf16x8 a[4], b[4];
#pragma unroll
      for (int i = 0; i < 4; ++i) {
        int row = wr * 64 + i * 16 + c16;
        int s = ((kk >> 3) + g) ^ (row & 7);  // swizzled ds_read slot
        a[i] = *reinterpret_cast<const bf16x8*>(&lA[row][s * 8]);
      }
#pragma unroll
      for (int j = 0; j < 4; ++j) {
        int row = wc * 64 + j * 16 + c16;
        int s = ((kk >> 3) + g) ^ (row & 7);
        b[j] = *reinterpret_cast<const bf16x8*>(&lB[row][s * 8]);
      }
#pragma unroll
      for (int i = 0; i < 4; ++i)
#pragma unroll
        for (int j = 0; j < 4; ++j)
          acc[i][j] = __builtin_amdgcn_mfma_f32_16x16x32_bf16(a[i], b[j], acc[i][j], 0, 0, 0);
    }
    __syncthreads();
  }

  // C/D layout (validated r4): col = lane&15, row = (lane>>4)*4 + reg
#pragma unroll
  for (int i = 0; i < 4; ++i)
#pragma unroll
    for (int r = 0; r < 4; ++r) {
      const size_t row = (size_t)(brow + wr * 64 + i * 16 + g * 4 + r);
      float* o = out + row * 4096 + bcol + wc * 64 + c16;
#pragma unroll
      for (int j = 0; j < 4; ++j) o[j * 16] = acc[i][j][r];
    }
}

// ---------- launch ----------
extern "C" void kernel_launch(void* const* d_in, const int* in_sizes, int n_in,
                              void* d_out, int out_size, void* d_ws, size_t ws_size,
                              hipStream_t stream) {
  (void)in_sizes; (void)n_in; (void)out_size; (void)ws_size;
  const float* in1   = (const float*)d_in[0];   // [16384][512]
  const float* in2   = (const float*)d_in[1];   // [512][512]
  const float* value = (const float*)d_in[2];   // [512][4096]
  float* out = (float*)d_out;                   // [16384][4096]

  unsigned short* vT    = (unsigned short*)d_ws;  // 4 MB   [4096][512] bf16
  unsigned short* Pb    = vT + 2097152;           // 16 MB  [16384][512] bf16
  unsigned short* in2hi = Pb + 8388608;           // 0.5 MB [512][512] bf16
  unsigned short* in2lo = in2hi + 262144;         // 0.5 MB

  k_vt<<<dim3(128, 16), dim3(256), 0, stream>>>(value, vT);
  k_split<<<dim3(256), dim3(256), 0, stream>>>(in2, in2hi, in2lo, 65536);
  k_qk<<<dim3(512), dim3(512), 0, stream>>>(in1, in2hi, in2lo, Pb);
  k_pv<<<dim3(4096), dim3(256), 0, stream>>>(Pb, vT, out);
}